// Round 1
// baseline (2921.344 us; speedup 1.0000x reference)
//
#include <hip/hip_runtime.h>

#define B_    8
#define N_    16384
#define K_    16
#define G_    4
#define CQ_   64
#define CV_   64
#define CQG_  16
#define CVG_  16
#define CLPE_ 16

// One thread per (b, g, n).
// Pass A: gather neighbor queries -> logits -> softmax -> centrality atomics.
// Pass B: gather neighbor values + xyz -> LPE enc -> write f_enc, accumulate out.
__global__ __launch_bounds__(256) void gtl_kernel(
    const float* __restrict__ xyz,
    const float* __restrict__ query,
    const float* __restrict__ value,
    const int*   __restrict__ nidx,
    const float* __restrict__ lpeW,
    const float* __restrict__ lpeB,
    const float* __restrict__ bnG,
    const float* __restrict__ bnB,
    const float* __restrict__ bnM,
    const float* __restrict__ bnV,
    float* __restrict__ out,
    float* __restrict__ fenc,
    float* __restrict__ cent)
{
    // Folded LPE+BN weights:
    //   relf = [d, r, c, nb] with r = c - nb
    //   t_c  = w0*d + (w1..3)·r + (w4..6)·c + (w7..9)·nb
    //        = w0*d + (w1+w4, w2+w5, w3+w6)·c + (w7-w1, w8-w2, w9-w3)·nb
    //   y_c  = relu(scale_c * t_c + shift_c),  scale = gamma*rsqrt(var+eps),
    //   shift = (lpe_b - mean)*scale + beta
    __shared__ float4 sA[CLPE_];  // scale*(center coeffs), w = shift
    __shared__ float4 sB[CLPE_];  // scale*(neighbor coeffs), w = scale*w0 (dist)

    const int t = threadIdx.x;
    if (t < CLPE_) {
        const float scale = bnG[t] * rsqrtf(bnV[t] + 1e-5f);
        const float shift = (lpeB[t] - bnM[t]) * scale + bnB[t];
        const float w0 = lpeW[t*10+0];
        const float w1 = lpeW[t*10+1], w2 = lpeW[t*10+2], w3 = lpeW[t*10+3];
        const float w4 = lpeW[t*10+4], w5 = lpeW[t*10+5], w6 = lpeW[t*10+6];
        const float w7 = lpeW[t*10+7], w8 = lpeW[t*10+8], w9 = lpeW[t*10+9];
        sA[t] = make_float4(scale*(w1+w4), scale*(w2+w5), scale*(w3+w6), shift);
        sB[t] = make_float4(scale*(w7-w1), scale*(w8-w2), scale*(w9-w3), scale*w0);
    }
    __syncthreads();

    const int gid = blockIdx.x * 256 + t;     // ((b*G + g)*N + n)
    const int n   = gid & (N_ - 1);
    const int bg  = gid >> 14;                 // b*G + g
    const int g   = bg & (G_ - 1);
    const int b   = bg >> 2;

    const float cx = xyz[(size_t)(b*N_ + n)*3 + 0];
    const float cy = xyz[(size_t)(b*N_ + n)*3 + 1];
    const float cz = xyz[(size_t)(b*N_ + n)*3 + 2];

    // neighbor indices (within-batch; idx_base just offsets to batch b)
    int idx[K_];
    {
        const int4* ip = (const int4*)(nidx + (size_t)(b*N_ + n) * K_);
        #pragma unroll
        for (int q4 = 0; q4 < K_/4; ++q4) {
            const int4 v = ip[q4];
            idx[q4*4+0] = v.x; idx[q4*4+1] = v.y;
            idx[q4*4+2] = v.z; idx[q4*4+3] = v.w;
        }
    }

    // ---- Pass A: attention logits ----
    const float* qb = query + (size_t)b*CQ_*N_ + (size_t)g*CQG_*N_;
    float lq[CQG_];
    #pragma unroll
    for (int c = 0; c < CQG_; ++c) lq[c] = qb[(size_t)c*N_ + n];

    float la[K_];
    #pragma unroll 4
    for (int k = 0; k < K_; ++k) {
        const float* qj = qb + idx[k];
        float s = 0.f;
        #pragma unroll
        for (int c = 0; c < CQG_; ++c) s = fmaf(lq[c], qj[(size_t)c*N_], s);
        la[k] = s;
    }

    // softmax over k
    float m = la[0];
    #pragma unroll
    for (int k = 1; k < K_; ++k) m = fmaxf(m, la[k]);
    float ssum = 0.f;
    #pragma unroll
    for (int k = 0; k < K_; ++k) { const float e = __expf(la[k] - m); la[k] = e; ssum += e; }
    const float inv = 1.f / ssum;
    #pragma unroll
    for (int k = 0; k < K_; ++k) la[k] *= inv;

    // centrality scatter-add
    float* cb = cent + (size_t)bg * N_;
    #pragma unroll
    for (int k = 0; k < K_; ++k) atomicAdd(cb + idx[k], la[k]);

    // per-point (k-invariant) LPE base
    float basec[CLPE_];
    #pragma unroll
    for (int c = 0; c < CLPE_; ++c) {
        const float4 a = sA[c];
        basec[c] = fmaf(a.x, cx, fmaf(a.y, cy, fmaf(a.z, cz, a.w)));
    }

    // ---- Pass B: values + LPE enc -> f_enc + out accumulation ----
    const float* vb = value + (size_t)b*CV_*N_ + (size_t)g*CVG_*N_;
    float accV[CVG_], accE[CLPE_];
    #pragma unroll
    for (int c = 0; c < CLPE_; ++c) { accV[c] = 0.f; accE[c] = 0.f; }

    float* fe = fenc + ((size_t)bg * CLPE_ * N_ + n) * K_;   // + c*N*K + k

    #pragma unroll 2
    for (int k = 0; k < K_; ++k) {
        const int j = idx[k];
        const float nx = xyz[(size_t)(b*N_ + j)*3 + 0];
        const float ny = xyz[(size_t)(b*N_ + j)*3 + 1];
        const float nz = xyz[(size_t)(b*N_ + j)*3 + 2];
        const float rx = cx - nx, ry = cy - ny, rz = cz - nz;
        const float d  = sqrtf(rx*rx + ry*ry + rz*rz);
        const float w  = la[k];
        const float* vj = vb + j;
        #pragma unroll
        for (int c = 0; c < CLPE_; ++c) {
            const float4 bb = sB[c];
            float e = basec[c];
            e = fmaf(bb.x, nx, e);
            e = fmaf(bb.y, ny, e);
            e = fmaf(bb.z, nz, e);
            e = fmaf(bb.w, d,  e);
            e = fmaxf(e, 0.f);
            fe[(size_t)c*(N_*K_) + k] = e;
            accE[c] = fmaf(w, e, accE[c]);
            accV[c] = fmaf(w, vj[(size_t)c*N_], accV[c]);
        }
    }

    // out[b, g*32 + c, n]
    float* ob = out + (size_t)bg * (CVG_ + CLPE_) * N_ + n;
    #pragma unroll
    for (int c = 0; c < CVG_; ++c)  ob[(size_t)c*N_]          = accV[c];
    #pragma unroll
    for (int c = 0; c < CLPE_; ++c) ob[(size_t)(CVG_+c)*N_]   = accE[c];
}

extern "C" void kernel_launch(void* const* d_in, const int* in_sizes, int n_in,
                              void* d_out, int out_size, void* d_ws, size_t ws_size,
                              hipStream_t stream) {
    (void)in_sizes; (void)n_in; (void)d_ws; (void)ws_size; (void)out_size;

    const float* xyz   = (const float*)d_in[0];
    const float* query = (const float*)d_in[1];
    const float* value = (const float*)d_in[2];
    const int*   nidx  = (const int*)  d_in[3];
    // d_in[4] = idx_base (b*N), implicit in our batch decomposition
    const float* lpeW  = (const float*)d_in[5];
    const float* lpeB  = (const float*)d_in[6];
    const float* bnG   = (const float*)d_in[7];
    const float* bnB   = (const float*)d_in[8];
    const float* bnM   = (const float*)d_in[9];
    const float* bnV   = (const float*)d_in[10];

    float* out  = (float*)d_out;                                  // B*128*N
    float* fenc = out  + (size_t)B_ * (G_*(CVG_+CLPE_)) * N_;     // B*G*16*N*K
    float* cent = fenc + (size_t)B_ * G_ * CLPE_ * N_ * K_;       // B*G*N

    // centrality is accumulated with atomics -> zero it first (d_out is poisoned)
    hipMemsetAsync(cent, 0, sizeof(float) * (size_t)B_ * G_ * N_, stream);

    const int total  = B_ * G_ * N_;          // 524288 threads
    const int block  = 256;
    const int grid   = total / block;         // 2048 blocks
    hipLaunchKernelGGL(gtl_kernel, dim3(grid), dim3(block), 0, stream,
                       xyz, query, value, nidx, lpeW, lpeB, bnG, bnB, bnM, bnV,
                       out, fenc, cent);
}

// Round 2
// 1242.035 us; speedup vs baseline: 2.3521x; 2.3521x over previous
//
#include <hip/hip_runtime.h>

#define B_    8
#define N_    16384
#define K_    16
#define G_    4
#define CQ_   64
#define CV_   64
#define CQG_  16
#define CVG_  16
#define CLPE_ 16
#define NT_   (B_*G_*N_)   // 524288 threads, one per (b,g,n)

// ---------------------------------------------------------------------------
// Kernel 1: transpose query/value from channel-major (b, 64, n) to point-major
// slabs (b, g, n, 16ch) so one neighbor gather = one 64B line. Also pack xyz
// into aligned float4. All reads and writes fully coalesced.
// ---------------------------------------------------------------------------
__global__ __launch_bounds__(256) void gtl_transpose(
    const float* __restrict__ query,
    const float* __restrict__ value,
    const float* __restrict__ xyz,
    float*  __restrict__ qT,
    float*  __restrict__ vT,
    float4* __restrict__ xyz4)
{
    const int gid = blockIdx.x * 256 + threadIdx.x;   // ((b*G+g)*N + n)
    const int n   = gid & (N_ - 1);
    const int bg  = gid >> 14;
    const int g   = bg & (G_ - 1);
    const int b   = bg >> 2;

    const float* qb = query + (size_t)b*CQ_*N_ + (size_t)g*CQG_*N_ + n;
    const float* vb = value + (size_t)b*CV_*N_ + (size_t)g*CVG_*N_ + n;
    float4* qo = (float4*)(qT + (size_t)gid * 16);
    float4* vo = (float4*)(vT + (size_t)gid * 16);

    #pragma unroll
    for (int q4 = 0; q4 < 4; ++q4) {
        float4 a, c;
        a.x = qb[(size_t)(q4*4+0)*N_]; a.y = qb[(size_t)(q4*4+1)*N_];
        a.z = qb[(size_t)(q4*4+2)*N_]; a.w = qb[(size_t)(q4*4+3)*N_];
        qo[q4] = a;
        c.x = vb[(size_t)(q4*4+0)*N_]; c.y = vb[(size_t)(q4*4+1)*N_];
        c.z = vb[(size_t)(q4*4+2)*N_]; c.w = vb[(size_t)(q4*4+3)*N_];
        vo[q4] = c;
    }

    if (g == 0) {  // one lane-set per (b,n) packs xyz
        const size_t p = (size_t)b*N_ + n;
        xyz4[p] = make_float4(xyz[p*3+0], xyz[p*3+1], xyz[p*3+2], 0.f);
    }
}

// ---------------------------------------------------------------------------
// Kernel 2: main fused pass. One thread per (b,g,n).
// ---------------------------------------------------------------------------
__global__ __launch_bounds__(256) void gtl_main(
    const float*  __restrict__ qT,
    const float*  __restrict__ vT,
    const float4* __restrict__ xyz4,
    const int*    __restrict__ nidx,
    const float*  __restrict__ lpeW,
    const float*  __restrict__ lpeB,
    const float*  __restrict__ bnG,
    const float*  __restrict__ bnB,
    const float*  __restrict__ bnM,
    const float*  __restrict__ bnV,
    float* __restrict__ out,
    float* __restrict__ fenc,
    float* __restrict__ cent)
{
    // Folded LPE+BN weights (see derivation in comments of R1):
    __shared__ float4 sA[CLPE_];  // scale*(center xyz coeffs), w = shift
    __shared__ float4 sB[CLPE_];  // scale*(neighbor xyz coeffs), w = scale*w0

    const int t = threadIdx.x;
    if (t < CLPE_) {
        const float scale = bnG[t] * rsqrtf(bnV[t] + 1e-5f);
        const float shift = (lpeB[t] - bnM[t]) * scale + bnB[t];
        const float w0 = lpeW[t*10+0];
        const float w1 = lpeW[t*10+1], w2 = lpeW[t*10+2], w3 = lpeW[t*10+3];
        const float w4 = lpeW[t*10+4], w5 = lpeW[t*10+5], w6 = lpeW[t*10+6];
        const float w7 = lpeW[t*10+7], w8 = lpeW[t*10+8], w9 = lpeW[t*10+9];
        sA[t] = make_float4(scale*(w1+w4), scale*(w2+w5), scale*(w3+w6), shift);
        sB[t] = make_float4(scale*(w7-w1), scale*(w8-w2), scale*(w9-w3), scale*w0);
    }
    __syncthreads();

    const int gid = blockIdx.x * 256 + t;
    const int n   = gid & (N_ - 1);
    const int bg  = gid >> 14;
    const int b   = bg >> 2;

    // neighbor indices: thread-contiguous 64B via int4
    int idx[K_];
    {
        const int4* ip = (const int4*)(nidx + (size_t)(b*N_ + n) * K_);
        #pragma unroll
        for (int q4 = 0; q4 < K_/4; ++q4) {
            const int4 v = ip[q4];
            idx[q4*4+0] = v.x; idx[q4*4+1] = v.y;
            idx[q4*4+2] = v.z; idx[q4*4+3] = v.w;
        }
    }

    // ---- Pass A: attention logits from point-major q slab ----
    const float4* qslab = (const float4*)(qT + (size_t)bg * N_ * 16);
    const float4 lq0 = qslab[(size_t)n*4+0];
    const float4 lq1 = qslab[(size_t)n*4+1];
    const float4 lq2 = qslab[(size_t)n*4+2];
    const float4 lq3 = qslab[(size_t)n*4+3];

    float la[K_];
    #pragma unroll 4
    for (int k = 0; k < K_; ++k) {
        const float4* qj = qslab + (size_t)idx[k]*4;   // one 64B line
        const float4 a = qj[0], bq = qj[1], cq = qj[2], dq = qj[3];
        float s;
        s = lq0.x*a.x;            s = fmaf(lq0.y, a.y, s);
        s = fmaf(lq0.z, a.z, s);  s = fmaf(lq0.w, a.w, s);
        s = fmaf(lq1.x, bq.x, s); s = fmaf(lq1.y, bq.y, s);
        s = fmaf(lq1.z, bq.z, s); s = fmaf(lq1.w, bq.w, s);
        s = fmaf(lq2.x, cq.x, s); s = fmaf(lq2.y, cq.y, s);
        s = fmaf(lq2.z, cq.z, s); s = fmaf(lq2.w, cq.w, s);
        s = fmaf(lq3.x, dq.x, s); s = fmaf(lq3.y, dq.y, s);
        s = fmaf(lq3.z, dq.z, s); s = fmaf(lq3.w, dq.w, s);
        la[k] = s;
    }

    // softmax over k
    float m = la[0];
    #pragma unroll
    for (int k = 1; k < K_; ++k) m = fmaxf(m, la[k]);
    float ssum = 0.f;
    #pragma unroll
    for (int k = 0; k < K_; ++k) { const float e = __expf(la[k] - m); la[k] = e; ssum += e; }
    const float inv = 1.f / ssum;
    #pragma unroll
    for (int k = 0; k < K_; ++k) la[k] *= inv;

    // centrality scatter-add
    {
        float* cb = cent + (size_t)bg * N_;
        #pragma unroll
        for (int k = 0; k < K_; ++k) atomicAdd(cb + idx[k], la[k]);
    }

    // center coords + k-invariant LPE base
    const float4 cpt = xyz4[(size_t)b*N_ + n];
    float basec[CLPE_];
    #pragma unroll
    for (int c = 0; c < CLPE_; ++c) {
        const float4 a = sA[c];
        basec[c] = fmaf(a.x, cpt.x, fmaf(a.y, cpt.y, fmaf(a.z, cpt.z, a.w)));
    }

    // ---- Pass B1: gather neighbor xyz (+dist) and values ----
    const float4* vslab = (const float4*)(vT + (size_t)bg * N_ * 16);
    float4 nbr[K_];          // (nx, ny, nz, dist)
    float accV[CVG_];
    #pragma unroll
    for (int c = 0; c < CVG_; ++c) accV[c] = 0.f;

    #pragma unroll 2
    for (int k = 0; k < K_; ++k) {
        const int j = idx[k];
        const float4 p = xyz4[(size_t)b*N_ + j];
        const float rx = cpt.x - p.x, ry = cpt.y - p.y, rz = cpt.z - p.z;
        const float d  = sqrtf(fmaf(rx,rx, fmaf(ry,ry, rz*rz)));
        nbr[k] = make_float4(p.x, p.y, p.z, d);
        const float w = la[k];
        const float4* vj = vslab + (size_t)j*4;        // one 64B line
        const float4 v0 = vj[0], v1 = vj[1], v2 = vj[2], v3 = vj[3];
        accV[0]  = fmaf(w, v0.x, accV[0]);  accV[1]  = fmaf(w, v0.y, accV[1]);
        accV[2]  = fmaf(w, v0.z, accV[2]);  accV[3]  = fmaf(w, v0.w, accV[3]);
        accV[4]  = fmaf(w, v1.x, accV[4]);  accV[5]  = fmaf(w, v1.y, accV[5]);
        accV[6]  = fmaf(w, v1.z, accV[6]);  accV[7]  = fmaf(w, v1.w, accV[7]);
        accV[8]  = fmaf(w, v2.x, accV[8]);  accV[9]  = fmaf(w, v2.y, accV[9]);
        accV[10] = fmaf(w, v2.z, accV[10]); accV[11] = fmaf(w, v2.w, accV[11]);
        accV[12] = fmaf(w, v3.x, accV[12]); accV[13] = fmaf(w, v3.y, accV[13]);
        accV[14] = fmaf(w, v3.z, accV[14]); accV[15] = fmaf(w, v3.w, accV[15]);
    }

    // ---- Pass B2: per-channel enc, full-line (4x float4) coalesced stores ----
    float* fe = fenc + ((size_t)bg * CLPE_ * N_ + n) * K_;
    float* ob = out  + (size_t)bg * (CVG_ + CLPE_) * N_ + n;

    #pragma unroll 2
    for (int c = 0; c < CLPE_; ++c) {
        const float4 wB = sB[c];
        const float base = basec[c];
        float e[K_];
        float acc = 0.f;
        #pragma unroll
        for (int k = 0; k < K_; ++k) {
            const float4 p = nbr[k];
            float tt = base;
            tt = fmaf(wB.x, p.x, tt);
            tt = fmaf(wB.y, p.y, tt);
            tt = fmaf(wB.z, p.z, tt);
            tt = fmaf(wB.w, p.w, tt);
            tt = fmaxf(tt, 0.f);
            e[k] = tt;
            acc  = fmaf(la[k], tt, acc);
        }
        float4* fo = (float4*)(fe + (size_t)c * (N_ * K_));   // thread-owned 64B line
        fo[0] = make_float4(e[0],  e[1],  e[2],  e[3]);
        fo[1] = make_float4(e[4],  e[5],  e[6],  e[7]);
        fo[2] = make_float4(e[8],  e[9],  e[10], e[11]);
        fo[3] = make_float4(e[12], e[13], e[14], e[15]);
        ob[(size_t)(CVG_ + c) * N_] = acc;                    // out enc-half
    }

    // out value-half
    #pragma unroll
    for (int c = 0; c < CVG_; ++c) ob[(size_t)c * N_] = accV[c];
}

// ---------------------------------------------------------------------------
// Fallback (R1 kernel, verified correct) if workspace is too small.
// ---------------------------------------------------------------------------
__global__ __launch_bounds__(256) void gtl_fallback(
    const float* __restrict__ xyz,
    const float* __restrict__ query,
    const float* __restrict__ value,
    const int*   __restrict__ nidx,
    const float* __restrict__ lpeW,
    const float* __restrict__ lpeB,
    const float* __restrict__ bnG,
    const float* __restrict__ bnB,
    const float* __restrict__ bnM,
    const float* __restrict__ bnV,
    float* __restrict__ out,
    float* __restrict__ fenc,
    float* __restrict__ cent)
{
    __shared__ float4 sA[CLPE_];
    __shared__ float4 sB[CLPE_];
    const int t = threadIdx.x;
    if (t < CLPE_) {
        const float scale = bnG[t] * rsqrtf(bnV[t] + 1e-5f);
        const float shift = (lpeB[t] - bnM[t]) * scale + bnB[t];
        const float w0 = lpeW[t*10+0];
        const float w1 = lpeW[t*10+1], w2 = lpeW[t*10+2], w3 = lpeW[t*10+3];
        const float w4 = lpeW[t*10+4], w5 = lpeW[t*10+5], w6 = lpeW[t*10+6];
        const float w7 = lpeW[t*10+7], w8 = lpeW[t*10+8], w9 = lpeW[t*10+9];
        sA[t] = make_float4(scale*(w1+w4), scale*(w2+w5), scale*(w3+w6), shift);
        sB[t] = make_float4(scale*(w7-w1), scale*(w8-w2), scale*(w9-w3), scale*w0);
    }
    __syncthreads();
    const int gid = blockIdx.x * 256 + t;
    const int n   = gid & (N_ - 1);
    const int bg  = gid >> 14;
    const int g   = bg & (G_ - 1);
    const int b   = bg >> 2;
    const float cx = xyz[(size_t)(b*N_ + n)*3 + 0];
    const float cy = xyz[(size_t)(b*N_ + n)*3 + 1];
    const float cz = xyz[(size_t)(b*N_ + n)*3 + 2];
    int idx[K_];
    const int4* ip = (const int4*)(nidx + (size_t)(b*N_ + n) * K_);
    #pragma unroll
    for (int q4 = 0; q4 < K_/4; ++q4) {
        const int4 v = ip[q4];
        idx[q4*4+0] = v.x; idx[q4*4+1] = v.y; idx[q4*4+2] = v.z; idx[q4*4+3] = v.w;
    }
    const float* qb = query + (size_t)b*CQ_*N_ + (size_t)g*CQG_*N_;
    float lq[CQG_];
    #pragma unroll
    for (int c = 0; c < CQG_; ++c) lq[c] = qb[(size_t)c*N_ + n];
    float la[K_];
    #pragma unroll 4
    for (int k = 0; k < K_; ++k) {
        const float* qj = qb + idx[k];
        float s = 0.f;
        #pragma unroll
        for (int c = 0; c < CQG_; ++c) s = fmaf(lq[c], qj[(size_t)c*N_], s);
        la[k] = s;
    }
    float m = la[0];
    #pragma unroll
    for (int k = 1; k < K_; ++k) m = fmaxf(m, la[k]);
    float ssum = 0.f;
    #pragma unroll
    for (int k = 0; k < K_; ++k) { const float e = __expf(la[k] - m); la[k] = e; ssum += e; }
    const float inv = 1.f / ssum;
    #pragma unroll
    for (int k = 0; k < K_; ++k) la[k] *= inv;
    float* cb = cent + (size_t)bg * N_;
    #pragma unroll
    for (int k = 0; k < K_; ++k) atomicAdd(cb + idx[k], la[k]);
    float basec[CLPE_];
    #pragma unroll
    for (int c = 0; c < CLPE_; ++c) {
        const float4 a = sA[c];
        basec[c] = fmaf(a.x, cx, fmaf(a.y, cy, fmaf(a.z, cz, a.w)));
    }
    const float* vb = value + (size_t)b*CV_*N_ + (size_t)g*CVG_*N_;
    float accV[CVG_], accE[CLPE_];
    #pragma unroll
    for (int c = 0; c < CLPE_; ++c) { accV[c] = 0.f; accE[c] = 0.f; }
    float* fe = fenc + ((size_t)bg * CLPE_ * N_ + n) * K_;
    #pragma unroll 2
    for (int k = 0; k < K_; ++k) {
        const int j = idx[k];
        const float nx = xyz[(size_t)(b*N_ + j)*3 + 0];
        const float ny = xyz[(size_t)(b*N_ + j)*3 + 1];
        const float nz = xyz[(size_t)(b*N_ + j)*3 + 2];
        const float rx = cx - nx, ry = cy - ny, rz = cz - nz;
        const float d  = sqrtf(rx*rx + ry*ry + rz*rz);
        const float w  = la[k];
        const float* vj = vb + j;
        #pragma unroll
        for (int c = 0; c < CLPE_; ++c) {
            const float4 bb = sB[c];
            float e = basec[c];
            e = fmaf(bb.x, nx, e); e = fmaf(bb.y, ny, e);
            e = fmaf(bb.z, nz, e); e = fmaf(bb.w, d,  e);
            e = fmaxf(e, 0.f);
            fe[(size_t)c*(N_*K_) + k] = e;
            accE[c] = fmaf(w, e, accE[c]);
            accV[c] = fmaf(w, vj[(size_t)c*N_], accV[c]);
        }
    }
    float* ob = out + (size_t)bg * (CVG_ + CLPE_) * N_ + n;
    #pragma unroll
    for (int c = 0; c < CVG_; ++c)  ob[(size_t)c*N_]        = accV[c];
    #pragma unroll
    for (int c = 0; c < CLPE_; ++c) ob[(size_t)(CVG_+c)*N_] = accE[c];
}

extern "C" void kernel_launch(void* const* d_in, const int* in_sizes, int n_in,
                              void* d_out, int out_size, void* d_ws, size_t ws_size,
                              hipStream_t stream) {
    (void)in_sizes; (void)n_in; (void)out_size;

    const float* xyz   = (const float*)d_in[0];
    const float* query = (const float*)d_in[1];
    const float* value = (const float*)d_in[2];
    const int*   nidx  = (const int*)  d_in[3];
    const float* lpeW  = (const float*)d_in[5];
    const float* lpeB  = (const float*)d_in[6];
    const float* bnG   = (const float*)d_in[7];
    const float* bnB   = (const float*)d_in[8];
    const float* bnM   = (const float*)d_in[9];
    const float* bnV   = (const float*)d_in[10];

    float* out  = (float*)d_out;                                  // B*128*N
    float* fenc = out  + (size_t)B_ * (G_*(CVG_+CLPE_)) * N_;     // B*G*16*N*K
    float* cent = fenc + (size_t)B_ * G_ * CLPE_ * N_ * K_;       // B*G*N

    hipMemsetAsync(cent, 0, sizeof(float) * (size_t)B_ * G_ * N_, stream);

    const size_t qT_bytes  = (size_t)NT_ * 16 * sizeof(float);    // 33.5 MB
    const size_t vT_bytes  = qT_bytes;
    const size_t xyz4_bytes = (size_t)B_ * N_ * sizeof(float4);   // 2 MB
    const size_t need = qT_bytes + vT_bytes + xyz4_bytes;

    const int grid = NT_ / 256;   // 2048 blocks

    if (ws_size >= need) {
        float*  qT   = (float*)d_ws;
        float*  vT   = qT + (size_t)NT_ * 16;
        float4* xyz4 = (float4*)(vT + (size_t)NT_ * 16);
        hipLaunchKernelGGL(gtl_transpose, dim3(grid), dim3(256), 0, stream,
                           query, value, xyz, qT, vT, xyz4);
        hipLaunchKernelGGL(gtl_main, dim3(grid), dim3(256), 0, stream,
                           qT, vT, xyz4, nidx, lpeW, lpeB, bnG, bnB, bnM, bnV,
                           out, fenc, cent);
    } else {
        hipLaunchKernelGGL(gtl_fallback, dim3(grid), dim3(256), 0, stream,
                           xyz, query, value, nidx, lpeW, lpeB, bnG, bnB, bnM, bnV,
                           out, fenc, cent);
    }
}